// Round 1
// baseline (130.103 us; speedup 1.0000x reference)
//
#include <hip/hip_runtime.h>
#include <cmath>

#define IMG      512
#define OUT      502            // 512 - 11 + 1
#define TW       64             // output tile width
#define TH       32             // output tile height
#define IW       74             // input tile width  (TW + 10)
#define PITCH    76             // LDS row pitch (floats, multiple of 4 -> 16B aligned rows)
#define NTHREADS 256
#define TILES_X  8              // ceil(502/64)
#define TILES_Y  16             // ceil(502/32)
#define NIMG     32
#define NBLOCKS  (TILES_X * TILES_Y * NIMG)

struct GaussW { float w[11]; };

// ---------------------------------------------------------------------------
// Main fused kernel: vertical blur (global->regs->LDS) then horizontal blur +
// SSIM map + block reduction. One block = 64x32 output pixels of one image.
// ---------------------------------------------------------------------------
__global__ __launch_bounds__(NTHREADS, 4)
void ssim_tile_kernel(const float* __restrict__ ypred,
                      const float* __restrict__ ytrue,
                      float* __restrict__ partials,
                      GaussW gw)
{
    // 5 vertically-blurred maps: vX, vY, vXX, vYY, vXY  (rows 0..31, cols 0..73)
    __shared__ __align__(16) float sV[5][TH * PITCH];
    __shared__ float wsum[4];

    const int t     = threadIdx.x;
    const int tileX = blockIdx.x, tileY = blockIdx.y, img = blockIdx.z;
    const int ox0   = tileX * TW;
    const int oy0   = tileY * TH;

    const float* __restrict__ Xp = ytrue + (size_t)img * IMG * IMG;  // X = y_true
    const float* __restrict__ Yp = ypred + (size_t)img * IMG * IMG;  // Y = y_pred

    // ---------------- Phase 1: vertical blur ----------------
    // 74 cols x 3 row-groups (11,11,10 rows) = 222 work items, one per thread.
    // Lane -> consecutive column => coalesced global row reads.
    if (t < IW * 3) {
        const int c    = t % IW;
        const int g    = t / IW;
        const int r0   = g * 11;
        const int jmax = (g == 2) ? 10 : 11;

        int gx = ox0 + c; if (gx > IMG - 1) gx = IMG - 1;   // clamp: only feeds masked outputs
        const float* __restrict__ Xc = Xp + gx;
        const float* __restrict__ Yc = Yp + gx;

        float acc[5][11];
        #pragma unroll
        for (int m = 0; m < 5; ++m)
            #pragma unroll
            for (int j = 0; j < 11; ++j) acc[m][j] = 0.f;

        #pragma unroll
        for (int k = 0; k < 21; ++k) {
            int gy = oy0 + r0 + k; if (gy > IMG - 1) gy = IMG - 1;  // clamp rows too
            const float x = Xc[(size_t)gy * IMG];
            const float y = Yc[(size_t)gy * IMG];
            const float xx = x * x, yy = y * y, xy = x * y;
            #pragma unroll
            for (int j = 0; j < 11; ++j) {
                if (k - j >= 0 && k - j <= 10) {          // constant-folds per (k,j)
                    const float w = gw.w[k - j];
                    acc[0][j] += w * x;
                    acc[1][j] += w * y;
                    acc[2][j] += w * xx;
                    acc[3][j] += w * yy;
                    acc[4][j] += w * xy;
                }
            }
        }

        #pragma unroll
        for (int j = 0; j < 11; ++j) {
            if (j < jmax) {
                const int o = (r0 + j) * PITCH + c;
                sV[0][o] = acc[0][j];
                sV[1][o] = acc[1][j];
                sV[2][o] = acc[2][j];
                sV[3][o] = acc[3][j];
                sV[4][o] = acc[4][j];
            }
        }
    }
    __syncthreads();

    // ---------------- Phase 2: horizontal blur + SSIM ----------------
    // Item = (col-group of 4, row): 16 x 32 = 512 items, 2 per thread.
    // 4 aligned float4 loads per map cover the 14-col window (cols cg*4 .. cg*4+15).
    const float C1 = 0.0001f;   // (0.01*1)^2
    const float C2 = 0.0009f;   // (0.03*1)^2
    float lsum = 0.f;

    #pragma unroll
    for (int it = 0; it < 2; ++it) {
        const int i   = t + it * NTHREADS;   // 0..511
        const int cg  = i & 15;
        const int row = i >> 4;

        float res[5][4];
        #pragma unroll
        for (int m = 0; m < 5; ++m) {
            const float4* p = reinterpret_cast<const float4*>(&sV[m][row * PITCH + cg * 4]);
            const float4 a = p[0], b = p[1], cq = p[2], d = p[3];
            const float win[16] = { a.x,  a.y,  a.z,  a.w,
                                    b.x,  b.y,  b.z,  b.w,
                                    cq.x, cq.y, cq.z, cq.w,
                                    d.x,  d.y,  d.z,  d.w };
            #pragma unroll
            for (int c = 0; c < 4; ++c) {
                float r = 0.f;
                #pragma unroll
                for (int k = 0; k < 11; ++k) r += gw.w[k] * win[c + k];
                res[m][c] = r;
            }
        }

        const int oy = oy0 + row;
        #pragma unroll
        for (int c = 0; c < 4; ++c) {
            const int ox = ox0 + cg * 4 + c;
            const float mu1 = res[0][c], mu2 = res[1][c];
            const float s1  = res[2][c] - mu1 * mu1;
            const float s2  = res[3][c] - mu2 * mu2;
            const float s12 = res[4][c] - mu1 * mu2;
            const float num = (2.f * mu1 * mu2 + C1) * (2.f * s12 + C2);
            const float den = (mu1 * mu1 + mu2 * mu2 + C1) * (s1 + s2 + C2);
            const float ssim = num / den;
            if (ox < OUT && oy < OUT) lsum += ssim;
        }
    }

    // ---------------- Block reduction ----------------
    #pragma unroll
    for (int off = 32; off > 0; off >>= 1) lsum += __shfl_down(lsum, off, 64);
    if ((t & 63) == 0) wsum[t >> 6] = lsum;
    __syncthreads();
    if (t == 0) {
        const float b = wsum[0] + wsum[1] + wsum[2] + wsum[3];
        partials[((size_t)img * TILES_Y + tileY) * TILES_X + tileX] = b;
    }
}

// ---------------------------------------------------------------------------
// Final reduction: 4096 partials -> 1 - mean
// ---------------------------------------------------------------------------
__global__ void ssim_reduce_kernel(const float* __restrict__ partials,
                                   float* __restrict__ out)
{
    __shared__ double ws[4];
    const int t = threadIdx.x;
    double s = 0.0;
    for (int i = t; i < NBLOCKS; i += 256) s += (double)partials[i];
    #pragma unroll
    for (int off = 32; off > 0; off >>= 1) s += __shfl_down(s, off, 64);
    if ((t & 63) == 0) ws[t >> 6] = s;
    __syncthreads();
    if (t == 0) {
        const double total = ws[0] + ws[1] + ws[2] + ws[3];
        const double mean  = total / ((double)OUT * (double)OUT * (double)NIMG);
        out[0] = (float)(1.0 - mean);
    }
}

extern "C" void kernel_launch(void* const* d_in, const int* in_sizes, int n_in,
                              void* d_out, int out_size, void* d_ws, size_t ws_size,
                              hipStream_t stream)
{
    const float* ypred = (const float*)d_in[0];   // y_pred
    const float* ytrue = (const float*)d_in[1];   // y_true
    float* out      = (float*)d_out;
    float* partials = (float*)d_ws;               // NBLOCKS * 4 B = 16 KB

    // Gaussian weights: float64 math + normalize, then cast — matches reference.
    GaussW gw;
    double g[11], sum = 0.0;
    for (int i = 0; i < 11; ++i) {
        const double c = (double)i - 5.0;
        g[i] = std::exp(-(c * c) / (2.0 * 1.5 * 1.5));
        sum += g[i];
    }
    for (int i = 0; i < 11; ++i) gw.w[i] = (float)(g[i] / sum);

    dim3 grid(TILES_X, TILES_Y, NIMG);
    ssim_tile_kernel<<<grid, NTHREADS, 0, stream>>>(ypred, ytrue, partials, gw);
    ssim_reduce_kernel<<<1, 256, 0, stream>>>(partials, out);
}

// Round 2
// 127.425 us; speedup vs baseline: 1.0210x; 1.0210x over previous
//
#include <hip/hip_runtime.h>
#include <cmath>

#define IMG      512
#define OUT      502            // 512 - 11 + 1
#define TW       64             // output tile width
#define TH       32             // output tile height
#define IW       74             // input tile width  (TW + 10)
#define PITCH    76             // LDS row pitch in floats (16B-aligned rows)
#define MOFF     (TH * PITCH)   // floats per map = 2432
#define NTHREADS 256
#define TILES_X  8
#define TILES_Y  16
#define NIMG     32
#define NBLOCKS  (TILES_X * TILES_Y * NIMG)

struct GaussW { float w[11]; };

// ---------------------------------------------------------------------------
// Fused SSIM tile kernel. One block = 64x32 outputs of one image.
// Edge tiles are SHIFTED INWARD (no clamped loads -> affine addressing);
// ownership predicate in phase 2 prevents double counting.
// ---------------------------------------------------------------------------
__global__ __launch_bounds__(NTHREADS, 3)
void ssim_tile_kernel(const float* __restrict__ ypred,
                      const float* __restrict__ ytrue,
                      float* __restrict__ partials,
                      GaussW gw)
{
    // 5 vertically-blurred maps, flat: [m*MOFF + row*PITCH + col]
    __shared__ __align__(16) float sV[5 * MOFF];
    __shared__ float wsum[4];

    const int t     = threadIdx.x;
    const int tileX = blockIdx.x, tileY = blockIdx.y, img = blockIdx.z;
    // shift last tiles inward so ALL loads are in-bounds (no clamps)
    const int ox0 = (tileX == TILES_X - 1) ? (OUT - TW) : tileX * TW;  // 438 max
    const int oy0 = (tileY == TILES_Y - 1) ? (OUT - TH) : tileY * TH;  // 470 max

    const size_t imgoff = (size_t)img * (IMG * IMG);
    const float* __restrict__ Xp = ytrue + imgoff;   // X = y_true
    const float* __restrict__ Yp = ypred + imgoff;   // Y = y_pred

    // ---------------- Phase 1: vertical blur (global -> regs -> LDS) -------
    // 74 cols x 3 row-groups (11,11,10 outputs) = 222 items, one per thread.
    // Lane -> consecutive column => coalesced global row reads.
    if (t < IW * 3) {
        const int c  = t % IW;
        const int g  = t / IW;
        const int r0 = g * 11;

        const float* __restrict__ Xc = Xp + (size_t)(oy0 + r0) * IMG + (ox0 + c);
        const float* __restrict__ Yc = Yp + (size_t)(oy0 + r0) * IMG + (ox0 + c);

        float acc[5][11];
        #pragma unroll
        for (int m = 0; m < 5; ++m)
            #pragma unroll
            for (int j = 0; j < 11; ++j) acc[m][j] = 0.f;

        // rows r0..r0+19 (all groups); row r0+20 only for g<2 (j=10 tap)
        #pragma unroll
        for (int k = 0; k < 20; ++k) {
            const float x = Xc[k * IMG];
            const float y = Yc[k * IMG];
            const float xx = x * x, yy = y * y, xy = x * y;
            #pragma unroll
            for (int j = 0; j < 11; ++j) {
                if (k - j >= 0 && k - j <= 10) {        // constant-folds per (k,j)
                    const float w = gw.w[k - j];
                    acc[0][j] += w * x;
                    acc[1][j] += w * y;
                    acc[2][j] += w * xx;
                    acc[3][j] += w * yy;
                    acc[4][j] += w * xy;
                }
            }
        }
        if (g < 2) {                                    // k = 20 -> j = 10 only
            const float x = Xc[20 * IMG];
            const float y = Yc[20 * IMG];
            const float w = gw.w[10];
            acc[0][10] += w * x;
            acc[1][10] += w * y;
            acc[2][10] += w * (x * x);
            acc[3][10] += w * (y * y);
            acc[4][10] += w * (x * y);
        }

        const int o0 = r0 * PITCH + c;
        #pragma unroll
        for (int j = 0; j < 10; ++j) {                  // rows r0..r0+9: all groups
            const int o = o0 + j * PITCH;
            sV[0 * MOFF + o] = acc[0][j];
            sV[1 * MOFF + o] = acc[1][j];
            sV[2 * MOFF + o] = acc[2][j];
            sV[3 * MOFF + o] = acc[3][j];
            sV[4 * MOFF + o] = acc[4][j];
        }
        if (g < 2) {                                    // row r0+10 (j=10)
            const int o = o0 + 10 * PITCH;
            sV[0 * MOFF + o] = acc[0][10];
            sV[1 * MOFF + o] = acc[1][10];
            sV[2 * MOFF + o] = acc[2][10];
            sV[3 * MOFF + o] = acc[3][10];
            sV[4 * MOFF + o] = acc[4][10];
        }
    }
    __syncthreads();

    // ---------------- Phase 2: horizontal blur + SSIM + reduce -------------
    // Item = (row = t&31, seg = t>>5): 8 output cols per thread.
    // Consecutive 8 lanes span 8 rows -> bank offsets 12*r mod 32 all
    // distinct -> conflict-free ds_read_b128.
    // 5 b128 per map (cols seg*8 .. seg*8+19, use 0..17), offsets immediate.
    const float C1 = 0.0001f;   // (0.01*1)^2
    const float C2 = 0.0009f;   // (0.03*1)^2

    const int row  = t & 31;
    const int seg  = t >> 5;
    const int base = row * PITCH + seg * 8;

    float res[5][8];
    #pragma unroll
    for (int m = 0; m < 5; ++m) {
        const float4 q0 = *reinterpret_cast<const float4*>(&sV[base + m * MOFF +  0]);
        const float4 q1 = *reinterpret_cast<const float4*>(&sV[base + m * MOFF +  4]);
        const float4 q2 = *reinterpret_cast<const float4*>(&sV[base + m * MOFF +  8]);
        const float4 q3 = *reinterpret_cast<const float4*>(&sV[base + m * MOFF + 12]);
        const float4 q4 = *reinterpret_cast<const float4*>(&sV[base + m * MOFF + 16]);
        const float win[20] = { q0.x, q0.y, q0.z, q0.w,
                                q1.x, q1.y, q1.z, q1.w,
                                q2.x, q2.y, q2.z, q2.w,
                                q3.x, q3.y, q3.z, q3.w,
                                q4.x, q4.y, q4.z, q4.w };
        #pragma unroll
        for (int c = 0; c < 8; ++c) {
            float r = 0.f;
            #pragma unroll
            for (int k = 0; k < 11; ++k) r += gw.w[k] * win[c + k];
            res[m][c] = r;
        }
    }

    const int  oy     = oy0 + row;
    const bool rowown = (oy >= tileY * TH);             // edge-shift ownership
    float lsum = 0.f;

    #pragma unroll
    for (int c = 0; c < 8; ++c) {
        const int  ox  = ox0 + seg * 8 + c;
        const bool own = rowown && (ox >= tileX * TW);
        const float mu1 = res[0][c], mu2 = res[1][c];
        const float s1  = res[2][c] - mu1 * mu1;
        const float s2  = res[3][c] - mu2 * mu2;
        const float s12 = res[4][c] - mu1 * mu2;
        const float num = (2.f * mu1 * mu2 + C1) * (2.f * s12 + C2);
        const float den = (mu1 * mu1 + mu2 * mu2 + C1) * (s1 + s2 + C2);
        const float ssim = num / den;
        lsum += own ? ssim : 0.f;
    }

    // ---------------- Block reduction ----------------
    #pragma unroll
    for (int off = 32; off > 0; off >>= 1) lsum += __shfl_down(lsum, off, 64);
    if ((t & 63) == 0) wsum[t >> 6] = lsum;
    __syncthreads();
    if (t == 0) {
        const float b = wsum[0] + wsum[1] + wsum[2] + wsum[3];
        partials[((size_t)img * TILES_Y + tileY) * TILES_X + tileX] = b;
    }
}

// ---------------------------------------------------------------------------
// Final reduction: 4096 partials -> 1 - mean
// ---------------------------------------------------------------------------
__global__ void ssim_reduce_kernel(const float* __restrict__ partials,
                                   float* __restrict__ out)
{
    __shared__ double ws[4];
    const int t = threadIdx.x;
    double s = 0.0;
    for (int i = t; i < NBLOCKS; i += 256) s += (double)partials[i];
    #pragma unroll
    for (int off = 32; off > 0; off >>= 1) s += __shfl_down(s, off, 64);
    if ((t & 63) == 0) ws[t >> 6] = s;
    __syncthreads();
    if (t == 0) {
        const double total = ws[0] + ws[1] + ws[2] + ws[3];
        const double mean  = total / ((double)OUT * (double)OUT * (double)NIMG);
        out[0] = (float)(1.0 - mean);
    }
}

extern "C" void kernel_launch(void* const* d_in, const int* in_sizes, int n_in,
                              void* d_out, int out_size, void* d_ws, size_t ws_size,
                              hipStream_t stream)
{
    const float* ypred = (const float*)d_in[0];   // y_pred
    const float* ytrue = (const float*)d_in[1];   // y_true
    float* out      = (float*)d_out;
    float* partials = (float*)d_ws;               // NBLOCKS * 4 B = 16 KB

    // Gaussian weights: float64 math + normalize, then cast — matches reference.
    GaussW gw;
    double g[11], sum = 0.0;
    for (int i = 0; i < 11; ++i) {
        const double c = (double)i - 5.0;
        g[i] = std::exp(-(c * c) / (2.0 * 1.5 * 1.5));
        sum += g[i];
    }
    for (int i = 0; i < 11; ++i) gw.w[i] = (float)(g[i] / sum);

    dim3 grid(TILES_X, TILES_Y, NIMG);
    ssim_tile_kernel<<<grid, NTHREADS, 0, stream>>>(ypred, ytrue, partials, gw);
    ssim_reduce_kernel<<<1, 256, 0, stream>>>(partials, out);
}